// Round 9
// baseline (357.595 us; speedup 1.0000x reference)
//
#include <hip/hip_runtime.h>
#include <stdint.h>

#define S_LEN  4096
#define HID    1024
#define NHEAD  2
#define HDIM   512
#define NSPLIT 4
#define KS_STRIDE 520   // 512 + 8 pad elems -> bank-floor on QK^T reads
#define LN_EPS 1e-5f

typedef __bf16 bf16x8 __attribute__((ext_vector_type(8)));
typedef float  f32x4  __attribute__((ext_vector_type(4)));

__device__ __forceinline__ float b2f(unsigned short u) {
    return __uint_as_float(((unsigned int)u) << 16);
}
__device__ __forceinline__ unsigned short f2b(float f) {
    unsigned int u = __float_as_uint(f);
    u += 0x7FFFu + ((u >> 16) & 1u);   // round-to-nearest-even
    return (unsigned short)(u >> 16);
}

// async 16B global->LDS (DMA; LDS dest must be wave-uniform base + lane*16)
__device__ __forceinline__ void async_cp16(const void* g, void* l) {
    __builtin_amdgcn_global_load_lds(
        (const __attribute__((address_space(1))) unsigned int*)g,
        (__attribute__((address_space(3))) unsigned int*)l, 16, 0, 0);
}

// -------- fp32->bf16 for 4 weight matrices (z=0..3) + semb (z==4) in one launch --------
__global__ void k_cvt4s(const float* __restrict__ i0, const float* __restrict__ i1,
                        const float* __restrict__ i2, const float* __restrict__ i3,
                        unsigned short* __restrict__ o0, unsigned short* __restrict__ o1,
                        unsigned short* __restrict__ o2, unsigned short* __restrict__ o3,
                        const float* __restrict__ Ws, const float* __restrict__ sd,
                        const float* __restrict__ bs, float* __restrict__ semb) {
    int z = blockIdx.y;
    if (z == 4) {
        int j = blockIdx.x * blockDim.x + threadIdx.x;
        if (j >= HID) return;
        float acc = bs[j];
        const float* row = Ws + j * 64;
        #pragma unroll
        for (int d = 0; d < 64; ++d) acc += row[d] * sd[d];
        semb[j] = acc;
        return;
    }
    const float* in = z == 0 ? i0 : z == 1 ? i1 : z == 2 ? i2 : i3;
    unsigned short* o = z == 0 ? o0 : z == 1 ? o1 : z == 2 ? o2 : o3;
    int i = (blockIdx.x * blockDim.x + threadIdx.x) * 8;
    float4 a = *(const float4*)(in + i);
    float4 b = *(const float4*)(in + i + 4);
    unsigned short r[8] = {f2b(a.x), f2b(a.y), f2b(a.z), f2b(a.w),
                           f2b(b.x), f2b(b.y), f2b(b.z), f2b(b.w)};
    *(uint4*)(o + i) = *(const uint4*)r;
}

// ---------------- Xb = bf16(X);  kv_in = bf16(X + semb) ----------------
__global__ void k_kvin(const float* __restrict__ X,
                       const float* __restrict__ semb,
                       unsigned short* __restrict__ Xb,
                       unsigned short* __restrict__ kv) {
    int idx = (blockIdx.x * blockDim.x + threadIdx.x) * 8;
    if (idx >= S_LEN * HID) return;
    int col = idx & (HID - 1);
    float4 a = *(const float4*)(X + idx);
    float4 b = *(const float4*)(X + idx + 4);
    unsigned short xo[8] = {f2b(a.x), f2b(a.y), f2b(a.z), f2b(a.w),
                            f2b(b.x), f2b(b.y), f2b(b.z), f2b(b.w)};
    *(uint4*)(Xb + idx) = *(const uint4*)xo;
    unsigned short o[8];
    o[0] = f2b(a.x + semb[col + 0]);
    o[1] = f2b(a.y + semb[col + 1]);
    o[2] = f2b(a.z + semb[col + 2]);
    o[3] = f2b(a.w + semb[col + 3]);
    o[4] = f2b(b.x + semb[col + 4]);
    o[5] = f2b(b.y + semb[col + 5]);
    o[6] = f2b(b.z + semb[col + 6]);
    o[7] = f2b(b.w + semb[col + 7]);
    *(uint4*)(kv + idx) = *(const uint4*)o;
}

// ---------------- 128x128 GEMM core (m97 structure): C = A @ B^T, bf16 out ----------------
__device__ __forceinline__
void gemm128(const unsigned short* __restrict__ A,
             const unsigned short* __restrict__ B,
             unsigned short* __restrict__ Cb,
             int nx, int ldc) {
    __shared__ unsigned short As[128 * 32];
    __shared__ unsigned short Bs[128 * 32];
    int tid  = threadIdx.x;
    int wave = tid >> 6, lane = tid & 63;
    int quad = lane >> 4, l16 = lane & 15;
    int wm = wave >> 1, wn = wave & 1;
    int m0 = (blockIdx.x / nx) * 128, n0 = (blockIdx.x % nx) * 128;

    f32x4 zero = {0.f, 0.f, 0.f, 0.f};
    f32x4 acc[4][4];
    #pragma unroll
    for (int i = 0; i < 4; ++i)
        #pragma unroll
        for (int j = 0; j < 4; ++j) acc[i][j] = zero;

    for (int k0 = 0; k0 < HID; k0 += 32) {
        #pragma unroll
        for (int i = 0; i < 2; ++i) {
            int c = tid + i * 256;   // LDS dest c*16B: wave-uniform base + lane*16 -> DMA-legal
            async_cp16(A + (m0 + (c >> 2)) * HID + k0 + (c & 3) * 8, As + c * 8);
            async_cp16(B + (n0 + (c >> 2)) * HID + k0 + (c & 3) * 8, Bs + c * 8);
        }
        __syncthreads();
        bf16x8 af[4], bfr[4];
        #pragma unroll
        for (int i = 0; i < 4; ++i)
            af[i] = *(const bf16x8*)(As + (wm * 64 + i * 16 + l16) * 32 + quad * 8);
        #pragma unroll
        for (int j = 0; j < 4; ++j)
            bfr[j] = *(const bf16x8*)(Bs + (wn * 64 + j * 16 + l16) * 32 + quad * 8);
        #pragma unroll
        for (int i = 0; i < 4; ++i)
            #pragma unroll
            for (int j = 0; j < 4; ++j)
                acc[i][j] = __builtin_amdgcn_mfma_f32_16x16x32_bf16(af[i], bfr[j], acc[i][j], 0, 0, 0);
        __syncthreads();
    }

    #pragma unroll
    for (int i = 0; i < 4; ++i) {
        int rbase = m0 + wm * 64 + i * 16 + quad * 4;  // C/D row = (lane>>4)*4 + reg
        #pragma unroll
        for (int j = 0; j < 4; ++j) {
            int col = n0 + wn * 64 + j * 16 + l16;     // C/D col = lane&15
            #pragma unroll
            for (int r = 0; r < 4; ++r)
                Cb[(size_t)(rbase + r) * ldc + col] = f2b(acc[i][j][r]);
        }
    }
}

// fused Q/K/V projections: blockIdx.z selects the GEMM (256 blocks each, 768 total = 3/CU)
__global__ __launch_bounds__(256)
void k_gemm_qkv(const unsigned short* __restrict__ Xb,
                const unsigned short* __restrict__ kvin,
                const unsigned short* __restrict__ Wqb,
                const unsigned short* __restrict__ Wkb,
                const unsigned short* __restrict__ Wvb,
                unsigned short* __restrict__ Qb,
                unsigned short* __restrict__ Kb,
                unsigned short* __restrict__ Vt) {
    int z = blockIdx.z;
    if (z == 0)      gemm128(Xb,   Wqb,  Qb,  8, HID);
    else if (z == 1) gemm128(kvin, Wkb,  Kb,  8, HID);
    else             gemm128(Wvb,  kvin, Vt, 32, S_LEN);   // V^T [HID][S_LEN]
}

// ---------------- out-projection 64x128 tile with fused residual (fp32 out) ----------------
__global__ __launch_bounds__(256)
void k_gemm_o(const unsigned short* __restrict__ A,
              const unsigned short* __restrict__ B,
              float* __restrict__ Cf,
              const float* __restrict__ Xres) {
    __shared__ unsigned short As[64 * 32];
    __shared__ unsigned short Bs[128 * 32];
    int tid  = threadIdx.x;
    int wave = tid >> 6, lane = tid & 63;
    int quad = lane >> 4, l16 = lane & 15;
    int m0 = (blockIdx.x >> 3) * 64, n0 = (blockIdx.x & 7) * 128;

    f32x4 zero = {0.f, 0.f, 0.f, 0.f};
    f32x4 acc[4][2];
    #pragma unroll
    for (int i = 0; i < 4; ++i)
        #pragma unroll
        for (int j = 0; j < 2; ++j) acc[i][j] = zero;

    for (int k0 = 0; k0 < HID; k0 += 32) {
        async_cp16(A + (m0 + (tid >> 2)) * HID + k0 + (tid & 3) * 8, As + tid * 8);
        #pragma unroll
        for (int i = 0; i < 2; ++i) {
            int c = tid + i * 256;
            async_cp16(B + (n0 + (c >> 2)) * HID + k0 + (c & 3) * 8, Bs + c * 8);
        }
        __syncthreads();
        bf16x8 af[4], bfr[2];
        #pragma unroll
        for (int i = 0; i < 4; ++i)
            af[i] = *(const bf16x8*)(As + (i * 16 + l16) * 32 + quad * 8);
        #pragma unroll
        for (int j = 0; j < 2; ++j)
            bfr[j] = *(const bf16x8*)(Bs + (wave * 32 + j * 16 + l16) * 32 + quad * 8);
        #pragma unroll
        for (int i = 0; i < 4; ++i)
            #pragma unroll
            for (int j = 0; j < 2; ++j)
                acc[i][j] = __builtin_amdgcn_mfma_f32_16x16x32_bf16(af[i], bfr[j], acc[i][j], 0, 0, 0);
        __syncthreads();
    }

    #pragma unroll
    for (int i = 0; i < 4; ++i) {
        int rbase = m0 + i * 16 + quad * 4;
        #pragma unroll
        for (int j = 0; j < 2; ++j) {
            int col = n0 + wave * 32 + j * 16 + l16;
            #pragma unroll
            for (int r = 0; r < 4; ++r) {
                size_t o = (size_t)(rbase + r) * HID + col;
                Cf[o] = acc[i][j][r] + Xres[o];
            }
        }
    }
}

// ---------------- flash attention: 64 queries x one (head, key-split of 1024) ----------------
// Fixed-max softmax (logits ~N(0,1), clamp 30). K double-buffered in LDS. V direct from
// global; ALL 8 V-frags prefetched BEFORE QK^T so their L2 latency hides under it.
// XCD swizzle: blockIdx.x = head*NSPLIT+split (8 values -> round-robin XCDs), y = qtile.
__global__ __launch_bounds__(256, 2)
void k_flash(const unsigned short* __restrict__ Q,
             const unsigned short* __restrict__ K,
             const unsigned short* __restrict__ Vt,   // [HID][S_LEN]
             const int* __restrict__ mask,
             unsigned short* __restrict__ Opart,      // [NSPLIT][S_LEN][HID] bf16 unnormalized
             float* __restrict__ Lbuf) {              // [NSPLIT][NHEAD][S_LEN]
    __shared__ unsigned short Ks[2][32 * KS_STRIDE];  // double-buffered [key][hd], padded
    __shared__ __bf16 Ps[64][40];                     // block-shared P [query][key], padded
    int tid  = threadIdx.x;
    int wave = tid >> 6, lane = tid & 63;
    int quad = lane >> 4, l16 = lane & 15;
    int head = blockIdx.x / NSPLIT, split = blockIdx.x % NSPLIT, qtile = blockIdx.y;

    // Q fragments (A-operand: A[m=lane&15][k=quad*8+j]), pinned in registers
    int qrow = qtile * 64 + wave * 16 + l16;
    const unsigned short* qp = Q + qrow * HID + head * HDIM;
    bf16x8 qf[16];
    #pragma unroll
    for (int t = 0; t < 16; ++t) qf[t] = *(const bf16x8*)(qp + t * 32 + quad * 8);

    float lsum[4];
    #pragma unroll
    for (int r = 0; r < 4; ++r) lsum[r] = 0.f;
    f32x4 zero = {0.f, 0.f, 0.f, 0.f};
    f32x4 oacc[4][8];                          // 64 q (4 m-tiles) x 128 hd (8 n-tiles)
    #pragma unroll
    for (int mt = 0; mt < 4; ++mt)
        #pragma unroll
        for (int nt = 0; nt < 8; ++nt) oacc[mt][nt] = zero;

    const float scale = 0.044194173824159216f; // 1/sqrt(512)
    const unsigned short* Kbase = K + head * HDIM;
    const unsigned short* Vbase = Vt + (size_t)(head * HDIM + wave * 128) * S_LEN;

    // prologue: stage K-tile for it=0 into buffer 0
    {
        int k0 = split * 1024;
        #pragma unroll
        for (int i = 0; i < 8; ++i) {
            int c = tid + i * 256;
            int row = c >> 6, col = (c & 63) * 8;
            async_cp16(Kbase + (k0 + row) * HID + col, Ks[0] + row * KS_STRIDE + col);
        }
    }

    int cur = 0;
    for (int it = 0; it < 32; ++it) {
        int k0 = split * 1024 + it * 32;
        __syncthreads();   // Ks[cur] DMA drained; prev iter's Ps reads complete

        // early V prefetch for ALL 8 n-tiles (no Ps dependency): latency hides under QK^T
        bf16x8 vfe[8];
        #pragma unroll
        for (int nt = 0; nt < 8; ++nt)
            vfe[nt] = *(const bf16x8*)(Vbase + (size_t)(nt * 16 + l16) * S_LEN + k0 + quad * 8);

        // S = Q K^T  (B-frag: B[k=quad*8+j][n=lane&15] = K[key=lane&15][hd])
        f32x4 sacc[2];
        sacc[0] = zero; sacc[1] = zero;
        #pragma unroll
        for (int nt = 0; nt < 2; ++nt)
            #pragma unroll
            for (int t = 0; t < 16; ++t) {
                bf16x8 kf = *(const bf16x8*)(Ks[cur] + (nt * 16 + l16) * KS_STRIDE + t * 32 + quad * 8);
                sacc[nt] = __builtin_amdgcn_mfma_f32_16x16x32_bf16(qf[t], kf, sacc[nt], 0, 0, 0);
            }

        bool keep0 = (head != 0) || (mask[k0 + l16] != 0);
        bool keep1 = (head != 0) || (mask[k0 + 16 + l16] != 0);

        // p = exp(s) with fixed max 0; write to block-shared P (rows wave*16+quad*4+r)
        #pragma unroll
        for (int r = 0; r < 4; ++r) {
            float p0 = keep0 ? __expf(fminf(sacc[0][r] * scale, 30.f)) : 0.f;
            float p1 = keep1 ? __expf(fminf(sacc[1][r] * scale, 30.f)) : 0.f;
            lsum[r] += p0 + p1;
            Ps[wave * 16 + quad * 4 + r][l16]      = (__bf16)p0;
            Ps[wave * 16 + quad * 4 + r][16 + l16] = (__bf16)p1;
        }
        __syncthreads();   // all waves' P visible before PV

        // prefetch next K-tile (DMA overlaps the PV phase; drained at next loop-top barrier)
        if (it < 31) {
            int kn = k0 + 32;
            #pragma unroll
            for (int i = 0; i < 8; ++i) {
                int c = tid + i * 256;
                int row = c >> 6, col = (c & 63) * 8;
                async_cp16(Kbase + (kn + row) * HID + col, Ks[cur ^ 1] + row * KS_STRIDE + col);
            }
        }

        // O += P @ V, hd-split: wave covers hd slice [wave*128, wave*128+128)
        bf16x8 pf[4];
        #pragma unroll
        for (int mt = 0; mt < 4; ++mt)
            pf[mt] = *(const bf16x8*)&Ps[mt * 16 + l16][quad * 8];
        #pragma unroll
        for (int nt = 0; nt < 8; ++nt) {
            #pragma unroll
            for (int mt = 0; mt < 4; ++mt)
                oacc[mt][nt] = __builtin_amdgcn_mfma_f32_16x16x32_bf16(pf[mt], vfe[nt], oacc[mt][nt], 0, 0, 0);
        }
        cur ^= 1;
    }

    // one l-reduction across the 16 lanes of this quad (rows wave*16 + quad*4 + r)
    #pragma unroll
    for (int r = 0; r < 4; ++r) {
        float s = lsum[r];
        #pragma unroll
        for (int off = 1; off < 16; off <<= 1)
            s += __shfl_xor(s, off, 64);
        lsum[r] = s;
    }
    int lrow = qtile * 64 + wave * 16 + quad * 4;
    if (l16 == 0) {
        #pragma unroll
        for (int r = 0; r < 4; ++r)
            Lbuf[(split * NHEAD + head) * S_LEN + lrow + r] = lsum[r];
    }
    // O epilogue: rows = qtile*64 + mt*16 + quad*4 + r, cols = head*512 + wave*128 + nt*16 + l16
    unsigned short* op = Opart + (size_t)split * S_LEN * HID;
    #pragma unroll
    for (int mt = 0; mt < 4; ++mt)
        #pragma unroll
        for (int nt = 0; nt < 8; ++nt)
            #pragma unroll
            for (int r = 0; r < 4; ++r)
                op[(qtile * 64 + mt * 16 + quad * 4 + r) * HID +
                   head * HDIM + wave * 128 + nt * 16 + l16] = f2b(oacc[mt][nt][r]);
}

// ---------------- combine NSPLIT key-splits -> ctx (bf16) ----------------
__global__ void k_combine(const unsigned short* __restrict__ Opart,
                          const float* __restrict__ Lbuf,
                          unsigned short* __restrict__ ctx) {
    const int SH = S_LEN * HID;
    int idx = blockIdx.x * blockDim.x + threadIdx.x;
    if (idx >= SH) return;
    int s = idx >> 10;
    int h = (idx >> 9) & 1;
    float l = 0.f, v = 0.f;
    #pragma unroll
    for (int z = 0; z < NSPLIT; ++z) {
        l += Lbuf[(z * NHEAD + h) * S_LEN + s];
        v += b2f(Opart[(size_t)z * SH + idx]);
    }
    ctx[idx] = f2b(v / l);
}

// ---------------- per-row LayerNorm over H=1024 (fp32 in, fp32 out) ----------------
__global__ __launch_bounds__(256)
void k_ln(const float* __restrict__ res,
          const float* __restrict__ w,
          const float* __restrict__ b,
          float* __restrict__ out) {
    __shared__ float red[8];
    int s = blockIdx.x, tid = threadIdx.x;
    const float* row = res + s * HID;
    float x[4], s1 = 0.f, s2 = 0.f;
    #pragma unroll
    for (int i = 0; i < 4; ++i) {
        x[i] = row[tid + i * 256];
        s1 += x[i]; s2 += x[i] * x[i];
    }
    #pragma unroll
    for (int off = 1; off < 64; off <<= 1) {
        s1 += __shfl_xor(s1, off, 64);
        s2 += __shfl_xor(s2, off, 64);
    }
    int wave = tid >> 6;
    if ((tid & 63) == 0) { red[wave] = s1; red[4 + wave] = s2; }
    __syncthreads();
    s1 = red[0] + red[1] + red[2] + red[3];
    s2 = red[4] + red[5] + red[6] + red[7];
    float mu   = s1 * (1.f / HID);
    float var  = s2 * (1.f / HID) - mu * mu;
    float rstd = rsqrtf(var + LN_EPS);
    #pragma unroll
    for (int i = 0; i < 4; ++i) {
        int col = tid + i * 256;
        out[s * HID + col] = (x[i] - mu) * rstd * w[col] + b[col];
    }
}

extern "C" void kernel_launch(void* const* d_in, const int* in_sizes, int n_in,
                              void* d_out, int out_size, void* d_ws, size_t ws_size,
                              hipStream_t stream) {
    const float* X   = (const float*)d_in[0];
    const float* sd  = (const float*)d_in[1];
    const int*   msk = (const int*)d_in[2];
    const float* Wq  = (const float*)d_in[3];
    const float* Wk  = (const float*)d_in[4];
    const float* Wv  = (const float*)d_in[5];
    const float* Wo  = (const float*)d_in[6];
    const float* Wsp = (const float*)d_in[7];
    const float* bsp = (const float*)d_in[8];
    const float* lw  = (const float*)d_in[9];
    const float* lb  = (const float*)d_in[10];
    float* out = (float*)d_out;

    char* ws = (char*)d_ws;
    const size_t MB = 1ull << 20;
    float*          semb  = (float*)(ws);                     // 4 KB
    float*          Lbuf  = (float*)(ws + (1ull << 16));      // 128 KB @64K
    unsigned short* Xb    = (unsigned short*)(ws + 1 * MB);   // 8 MB bf16 X
    unsigned short* kvin  = (unsigned short*)(ws + 9 * MB);   // 8 MB
    unsigned short* Qb    = (unsigned short*)(ws + 17 * MB);  // 8 MB (dead after flash)
    unsigned short* Kb    = (unsigned short*)(ws + 25 * MB);  // 8 MB (dead after flash)
    unsigned short* Vt    = (unsigned short*)(ws + 33 * MB);  // 8 MB [HID][S_LEN]
    unsigned short* ctx   = (unsigned short*)(ws + 41 * MB);  // 8 MB
    unsigned short* Wqb   = (unsigned short*)(ws + 49 * MB);  // 2 MB
    unsigned short* Wkb   = (unsigned short*)(ws + 51 * MB);  // 2 MB
    unsigned short* Wvb   = (unsigned short*)(ws + 53 * MB);  // 2 MB
    unsigned short* Wob   = (unsigned short*)(ws + 55 * MB);  // 2 MB
    float*          resf  = (float*)(ws + 17 * MB);           // 16 MB, overlays dead Qb/Kb
    unsigned short* Opart = (unsigned short*)(ws + 57 * MB);  // 32 MB bf16 [4][S][H] -> 89 MB total

    const int SH = S_LEN * HID;   // 4M
    const int WW = HID * HID;     // 1M

    // weights->bf16 (z=0..3) + semb (z=4) in one dispatch
    k_cvt4s<<<dim3(WW / 8 / 256, 5), dim3(256), 0, stream>>>(
        Wq, Wk, Wv, Wo, Wqb, Wkb, Wvb, Wob, Wsp, sd, bsp, semb);

    k_kvin<<<dim3(SH / 8 / 256), dim3(256), 0, stream>>>(X, semb, Xb, kvin);

    // fused Q/K/V projections, 128x128 tiles: z=0 Q, z=1 K, z=2 V^T  -> 768 blocks, 3/CU
    k_gemm_qkv<<<dim3(256, 1, 3), dim3(256), 0, stream>>>(Xb, kvin, Wqb, Wkb, Wvb, Qb, Kb, Vt);

    // XCD swizzle: x = head*NSPLIT+split (8), y = qtile (64)
    k_flash<<<dim3(NHEAD * NSPLIT, S_LEN / 64), dim3(256), 0, stream>>>(
        Qb, Kb, Vt, msk, Opart, Lbuf);

    k_combine<<<dim3(SH / 256), dim3(256), 0, stream>>>(Opart, Lbuf, ctx);
    k_gemm_o<<<dim3(512), dim3(256), 0, stream>>>(ctx, Wob, resf, X);
    k_ln<<<dim3(S_LEN), dim3(256), 0, stream>>>(resf, lw, lb, out);
}

// Round 10
// 308.285 us; speedup vs baseline: 1.1599x; 1.1599x over previous
//
#include <hip/hip_runtime.h>
#include <stdint.h>

#define S_LEN  4096
#define HID    1024
#define NHEAD  2
#define HDIM   512
#define NSPLIT 4
#define KS_STRIDE 520   // 512 + 8 pad elems -> bank-floor on QK^T reads
#define LN_EPS 1e-5f

typedef __bf16 bf16x8 __attribute__((ext_vector_type(8)));
typedef float  f32x4  __attribute__((ext_vector_type(4)));

__device__ __forceinline__ float b2f(unsigned short u) {
    return __uint_as_float(((unsigned int)u) << 16);
}
__device__ __forceinline__ unsigned short f2b(float f) {
    unsigned int u = __float_as_uint(f);
    u += 0x7FFFu + ((u >> 16) & 1u);   // round-to-nearest-even
    return (unsigned short)(u >> 16);
}

// async 16B global->LDS (DMA; LDS dest must be wave-uniform base + lane*16)
__device__ __forceinline__ void async_cp16(const void* g, void* l) {
    __builtin_amdgcn_global_load_lds(
        (const __attribute__((address_space(1))) unsigned int*)g,
        (__attribute__((address_space(3))) unsigned int*)l, 16, 0, 0);
}

// -------- fp32->bf16 for 4 weight matrices (z=0..3) + semb (z==4) in one launch --------
__global__ void k_cvt4s(const float* __restrict__ i0, const float* __restrict__ i1,
                        const float* __restrict__ i2, const float* __restrict__ i3,
                        unsigned short* __restrict__ o0, unsigned short* __restrict__ o1,
                        unsigned short* __restrict__ o2, unsigned short* __restrict__ o3,
                        const float* __restrict__ Ws, const float* __restrict__ sd,
                        const float* __restrict__ bs, float* __restrict__ semb) {
    int z = blockIdx.y;
    if (z == 4) {
        int j = blockIdx.x * blockDim.x + threadIdx.x;
        if (j >= HID) return;
        float acc = bs[j];
        const float* row = Ws + j * 64;
        #pragma unroll
        for (int d = 0; d < 64; ++d) acc += row[d] * sd[d];
        semb[j] = acc;
        return;
    }
    const float* in = z == 0 ? i0 : z == 1 ? i1 : z == 2 ? i2 : i3;
    unsigned short* o = z == 0 ? o0 : z == 1 ? o1 : z == 2 ? o2 : o3;
    int i = (blockIdx.x * blockDim.x + threadIdx.x) * 8;
    float4 a = *(const float4*)(in + i);
    float4 b = *(const float4*)(in + i + 4);
    unsigned short r[8] = {f2b(a.x), f2b(a.y), f2b(a.z), f2b(a.w),
                           f2b(b.x), f2b(b.y), f2b(b.z), f2b(b.w)};
    *(uint4*)(o + i) = *(const uint4*)r;
}

// ---------------- Xb = bf16(X);  kv_in = bf16(X + semb) ----------------
__global__ void k_kvin(const float* __restrict__ X,
                       const float* __restrict__ semb,
                       unsigned short* __restrict__ Xb,
                       unsigned short* __restrict__ kv) {
    int idx = (blockIdx.x * blockDim.x + threadIdx.x) * 8;
    if (idx >= S_LEN * HID) return;
    int col = idx & (HID - 1);
    float4 a = *(const float4*)(X + idx);
    float4 b = *(const float4*)(X + idx + 4);
    unsigned short xo[8] = {f2b(a.x), f2b(a.y), f2b(a.z), f2b(a.w),
                            f2b(b.x), f2b(b.y), f2b(b.z), f2b(b.w)};
    *(uint4*)(Xb + idx) = *(const uint4*)xo;
    unsigned short o[8];
    o[0] = f2b(a.x + semb[col + 0]);
    o[1] = f2b(a.y + semb[col + 1]);
    o[2] = f2b(a.z + semb[col + 2]);
    o[3] = f2b(a.w + semb[col + 3]);
    o[4] = f2b(b.x + semb[col + 4]);
    o[5] = f2b(b.y + semb[col + 5]);
    o[6] = f2b(b.z + semb[col + 6]);
    o[7] = f2b(b.w + semb[col + 7]);
    *(uint4*)(kv + idx) = *(const uint4*)o;
}

// ---------------- 128x128 GEMM core (m97 structure): C = A @ B^T, bf16 out ----------------
__device__ __forceinline__
void gemm128(const unsigned short* __restrict__ A,
             const unsigned short* __restrict__ B,
             unsigned short* __restrict__ Cb,
             int nx, int ldc) {
    __shared__ unsigned short As[128 * 32];
    __shared__ unsigned short Bs[128 * 32];
    int tid  = threadIdx.x;
    int wave = tid >> 6, lane = tid & 63;
    int quad = lane >> 4, l16 = lane & 15;
    int wm = wave >> 1, wn = wave & 1;
    int m0 = (blockIdx.x / nx) * 128, n0 = (blockIdx.x % nx) * 128;

    f32x4 zero = {0.f, 0.f, 0.f, 0.f};
    f32x4 acc[4][4];
    #pragma unroll
    for (int i = 0; i < 4; ++i)
        #pragma unroll
        for (int j = 0; j < 4; ++j) acc[i][j] = zero;

    for (int k0 = 0; k0 < HID; k0 += 32) {
        #pragma unroll
        for (int i = 0; i < 2; ++i) {
            int c = tid + i * 256;   // LDS dest c*16B: wave-uniform base + lane*16 -> DMA-legal
            async_cp16(A + (m0 + (c >> 2)) * HID + k0 + (c & 3) * 8, As + c * 8);
            async_cp16(B + (n0 + (c >> 2)) * HID + k0 + (c & 3) * 8, Bs + c * 8);
        }
        __syncthreads();
        bf16x8 af[4], bfr[4];
        #pragma unroll
        for (int i = 0; i < 4; ++i)
            af[i] = *(const bf16x8*)(As + (wm * 64 + i * 16 + l16) * 32 + quad * 8);
        #pragma unroll
        for (int j = 0; j < 4; ++j)
            bfr[j] = *(const bf16x8*)(Bs + (wn * 64 + j * 16 + l16) * 32 + quad * 8);
        #pragma unroll
        for (int i = 0; i < 4; ++i)
            #pragma unroll
            for (int j = 0; j < 4; ++j)
                acc[i][j] = __builtin_amdgcn_mfma_f32_16x16x32_bf16(af[i], bfr[j], acc[i][j], 0, 0, 0);
        __syncthreads();
    }

    #pragma unroll
    for (int i = 0; i < 4; ++i) {
        int rbase = m0 + wm * 64 + i * 16 + quad * 4;  // C/D row = (lane>>4)*4 + reg
        #pragma unroll
        for (int j = 0; j < 4; ++j) {
            int col = n0 + wn * 64 + j * 16 + l16;     // C/D col = lane&15
            #pragma unroll
            for (int r = 0; r < 4; ++r)
                Cb[(size_t)(rbase + r) * ldc + col] = f2b(acc[i][j][r]);
        }
    }
}

// fused Q/K/V projections: blockIdx.z selects the GEMM (256 blocks each, 768 total = 3/CU)
__global__ __launch_bounds__(256)
void k_gemm_qkv(const unsigned short* __restrict__ Xb,
                const unsigned short* __restrict__ kvin,
                const unsigned short* __restrict__ Wqb,
                const unsigned short* __restrict__ Wkb,
                const unsigned short* __restrict__ Wvb,
                unsigned short* __restrict__ Qb,
                unsigned short* __restrict__ Kb,
                unsigned short* __restrict__ Vt) {
    int z = blockIdx.z;
    if (z == 0)      gemm128(Xb,   Wqb,  Qb,  8, HID);
    else if (z == 1) gemm128(kvin, Wkb,  Kb,  8, HID);
    else             gemm128(Wvb,  kvin, Vt, 32, S_LEN);   // V^T [HID][S_LEN]
}

// ---------------- out-projection 64x128 tile with fused residual (fp32 out) ----------------
__global__ __launch_bounds__(256)
void k_gemm_o(const unsigned short* __restrict__ A,
              const unsigned short* __restrict__ B,
              float* __restrict__ Cf,
              const float* __restrict__ Xres) {
    __shared__ unsigned short As[64 * 32];
    __shared__ unsigned short Bs[128 * 32];
    int tid  = threadIdx.x;
    int wave = tid >> 6, lane = tid & 63;
    int quad = lane >> 4, l16 = lane & 15;
    int m0 = (blockIdx.x >> 3) * 64, n0 = (blockIdx.x & 7) * 128;

    f32x4 zero = {0.f, 0.f, 0.f, 0.f};
    f32x4 acc[4][2];
    #pragma unroll
    for (int i = 0; i < 4; ++i)
        #pragma unroll
        for (int j = 0; j < 2; ++j) acc[i][j] = zero;

    for (int k0 = 0; k0 < HID; k0 += 32) {
        async_cp16(A + (m0 + (tid >> 2)) * HID + k0 + (tid & 3) * 8, As + tid * 8);
        #pragma unroll
        for (int i = 0; i < 2; ++i) {
            int c = tid + i * 256;
            async_cp16(B + (n0 + (c >> 2)) * HID + k0 + (c & 3) * 8, Bs + c * 8);
        }
        __syncthreads();
        bf16x8 af[4], bfr[2];
        #pragma unroll
        for (int i = 0; i < 4; ++i)
            af[i] = *(const bf16x8*)(As + (i * 16 + l16) * 32 + quad * 8);
        #pragma unroll
        for (int j = 0; j < 2; ++j)
            bfr[j] = *(const bf16x8*)(Bs + (wave * 32 + j * 16 + l16) * 32 + quad * 8);
        #pragma unroll
        for (int i = 0; i < 4; ++i)
            #pragma unroll
            for (int j = 0; j < 2; ++j)
                acc[i][j] = __builtin_amdgcn_mfma_f32_16x16x32_bf16(af[i], bfr[j], acc[i][j], 0, 0, 0);
        __syncthreads();
    }

    #pragma unroll
    for (int i = 0; i < 4; ++i) {
        int rbase = m0 + i * 16 + quad * 4;
        #pragma unroll
        for (int j = 0; j < 2; ++j) {
            int col = n0 + wave * 32 + j * 16 + l16;
            #pragma unroll
            for (int r = 0; r < 4; ++r) {
                size_t o = (size_t)(rbase + r) * HID + col;
                Cf[o] = acc[i][j][r] + Xres[o];
            }
        }
    }
}

// ---------------- flash attention: 64 queries x one (head, key-split of 1024) ----------------
// Fixed-max softmax (logits ~N(0,1), clamp 30). K double-buffered in LDS. V direct from
// global; FIRST 4 V-frags prefetched before QK^T (R7-proven — 8 early spills to scratch,
// R9 regression: FETCH/WRITE doubled at constant VGPR_Count=128). XCD swizzle on x.
__global__ __launch_bounds__(256, 2)
void k_flash(const unsigned short* __restrict__ Q,
             const unsigned short* __restrict__ K,
             const unsigned short* __restrict__ Vt,   // [HID][S_LEN]
             const int* __restrict__ mask,
             unsigned short* __restrict__ Opart,      // [NSPLIT][S_LEN][HID] bf16 unnormalized
             float* __restrict__ Lbuf) {              // [NSPLIT][NHEAD][S_LEN]
    __shared__ unsigned short Ks[2][32 * KS_STRIDE];  // double-buffered [key][hd], padded
    __shared__ __bf16 Ps[64][40];                     // block-shared P [query][key], padded
    int tid  = threadIdx.x;
    int wave = tid >> 6, lane = tid & 63;
    int quad = lane >> 4, l16 = lane & 15;
    int head = blockIdx.x / NSPLIT, split = blockIdx.x % NSPLIT, qtile = blockIdx.y;

    // Q fragments (A-operand: A[m=lane&15][k=quad*8+j]), pinned in registers
    int qrow = qtile * 64 + wave * 16 + l16;
    const unsigned short* qp = Q + qrow * HID + head * HDIM;
    bf16x8 qf[16];
    #pragma unroll
    for (int t = 0; t < 16; ++t) qf[t] = *(const bf16x8*)(qp + t * 32 + quad * 8);

    float lsum[4];
    #pragma unroll
    for (int r = 0; r < 4; ++r) lsum[r] = 0.f;
    f32x4 zero = {0.f, 0.f, 0.f, 0.f};
    f32x4 oacc[4][8];                          // 64 q (4 m-tiles) x 128 hd (8 n-tiles)
    #pragma unroll
    for (int mt = 0; mt < 4; ++mt)
        #pragma unroll
        for (int nt = 0; nt < 8; ++nt) oacc[mt][nt] = zero;

    const float scale = 0.044194173824159216f; // 1/sqrt(512)
    const unsigned short* Kbase = K + head * HDIM;
    const unsigned short* Vbase = Vt + (size_t)(head * HDIM + wave * 128) * S_LEN;

    // prologue: stage K-tile for it=0 into buffer 0
    {
        int k0 = split * 1024;
        #pragma unroll
        for (int i = 0; i < 8; ++i) {
            int c = tid + i * 256;
            int row = c >> 6, col = (c & 63) * 8;
            async_cp16(Kbase + (k0 + row) * HID + col, Ks[0] + row * KS_STRIDE + col);
        }
    }

    int cur = 0;
    for (int it = 0; it < 32; ++it) {
        int k0 = split * 1024 + it * 32;
        __syncthreads();   // Ks[cur] DMA drained; prev iter's Ps reads complete

        // early V prefetch (4 frags only — 8 exceeds the live-range budget and spills)
        bf16x8 vfe[4];
        #pragma unroll
        for (int nt = 0; nt < 4; ++nt)
            vfe[nt] = *(const bf16x8*)(Vbase + (size_t)(nt * 16 + l16) * S_LEN + k0 + quad * 8);

        // S = Q K^T  (B-frag: B[k=quad*8+j][n=lane&15] = K[key=lane&15][hd])
        f32x4 sacc[2];
        sacc[0] = zero; sacc[1] = zero;
        #pragma unroll
        for (int nt = 0; nt < 2; ++nt)
            #pragma unroll
            for (int t = 0; t < 16; ++t) {
                bf16x8 kf = *(const bf16x8*)(Ks[cur] + (nt * 16 + l16) * KS_STRIDE + t * 32 + quad * 8);
                sacc[nt] = __builtin_amdgcn_mfma_f32_16x16x32_bf16(qf[t], kf, sacc[nt], 0, 0, 0);
            }

        bool keep0 = (head != 0) || (mask[k0 + l16] != 0);
        bool keep1 = (head != 0) || (mask[k0 + 16 + l16] != 0);

        // p = exp(s) with fixed max 0; write to block-shared P (rows wave*16+quad*4+r)
        #pragma unroll
        for (int r = 0; r < 4; ++r) {
            float p0 = keep0 ? __expf(fminf(sacc[0][r] * scale, 30.f)) : 0.f;
            float p1 = keep1 ? __expf(fminf(sacc[1][r] * scale, 30.f)) : 0.f;
            lsum[r] += p0 + p1;
            Ps[wave * 16 + quad * 4 + r][l16]      = (__bf16)p0;
            Ps[wave * 16 + quad * 4 + r][16 + l16] = (__bf16)p1;
        }
        __syncthreads();   // all waves' P visible before PV

        // prefetch next K-tile (DMA overlaps the PV phase; drained at next loop-top barrier)
        if (it < 31) {
            int kn = k0 + 32;
            #pragma unroll
            for (int i = 0; i < 8; ++i) {
                int c = tid + i * 256;
                int row = c >> 6, col = (c & 63) * 8;
                async_cp16(Kbase + (kn + row) * HID + col, Ks[cur ^ 1] + row * KS_STRIDE + col);
            }
        }

        // O += P @ V, hd-split: wave covers hd slice [wave*128, wave*128+128)
        bf16x8 pf[4];
        #pragma unroll
        for (int mt = 0; mt < 4; ++mt)
            pf[mt] = *(const bf16x8*)&Ps[mt * 16 + l16][quad * 8];
        #pragma unroll
        for (int nt = 0; nt < 8; ++nt) {
            bf16x8 vf = (nt < 4) ? vfe[nt]
                : *(const bf16x8*)(Vbase + (size_t)(nt * 16 + l16) * S_LEN + k0 + quad * 8);
            #pragma unroll
            for (int mt = 0; mt < 4; ++mt)
                oacc[mt][nt] = __builtin_amdgcn_mfma_f32_16x16x32_bf16(pf[mt], vf, oacc[mt][nt], 0, 0, 0);
        }
        cur ^= 1;
    }

    // one l-reduction across the 16 lanes of this quad (rows wave*16 + quad*4 + r)
    #pragma unroll
    for (int r = 0; r < 4; ++r) {
        float s = lsum[r];
        #pragma unroll
        for (int off = 1; off < 16; off <<= 1)
            s += __shfl_xor(s, off, 64);
        lsum[r] = s;
    }
    int lrow = qtile * 64 + wave * 16 + quad * 4;
    if (l16 == 0) {
        #pragma unroll
        for (int r = 0; r < 4; ++r)
            Lbuf[(split * NHEAD + head) * S_LEN + lrow + r] = lsum[r];
    }
    // O epilogue: rows = qtile*64 + mt*16 + quad*4 + r, cols = head*512 + wave*128 + nt*16 + l16
    unsigned short* op = Opart + (size_t)split * S_LEN * HID;
    #pragma unroll
    for (int mt = 0; mt < 4; ++mt)
        #pragma unroll
        for (int nt = 0; nt < 8; ++nt)
            #pragma unroll
            for (int r = 0; r < 4; ++r)
                op[(qtile * 64 + mt * 16 + quad * 4 + r) * HID +
                   head * HDIM + wave * 128 + nt * 16 + l16] = f2b(oacc[mt][nt][r]);
}

// ---------------- combine NSPLIT key-splits -> ctx (bf16) ----------------
__global__ void k_combine(const unsigned short* __restrict__ Opart,
                          const float* __restrict__ Lbuf,
                          unsigned short* __restrict__ ctx) {
    const int SH = S_LEN * HID;
    int idx = blockIdx.x * blockDim.x + threadIdx.x;
    if (idx >= SH) return;
    int s = idx >> 10;
    int h = (idx >> 9) & 1;
    float l = 0.f, v = 0.f;
    #pragma unroll
    for (int z = 0; z < NSPLIT; ++z) {
        l += Lbuf[(z * NHEAD + h) * S_LEN + s];
        v += b2f(Opart[(size_t)z * SH + idx]);
    }
    ctx[idx] = f2b(v / l);
}

// ---------------- per-row LayerNorm over H=1024 (fp32 in, fp32 out) ----------------
__global__ __launch_bounds__(256)
void k_ln(const float* __restrict__ res,
          const float* __restrict__ w,
          const float* __restrict__ b,
          float* __restrict__ out) {
    __shared__ float red[8];
    int s = blockIdx.x, tid = threadIdx.x;
    const float* row = res + s * HID;
    float x[4], s1 = 0.f, s2 = 0.f;
    #pragma unroll
    for (int i = 0; i < 4; ++i) {
        x[i] = row[tid + i * 256];
        s1 += x[i]; s2 += x[i] * x[i];
    }
    #pragma unroll
    for (int off = 1; off < 64; off <<= 1) {
        s1 += __shfl_xor(s1, off, 64);
        s2 += __shfl_xor(s2, off, 64);
    }
    int wave = tid >> 6;
    if ((tid & 63) == 0) { red[wave] = s1; red[4 + wave] = s2; }
    __syncthreads();
    s1 = red[0] + red[1] + red[2] + red[3];
    s2 = red[4] + red[5] + red[6] + red[7];
    float mu   = s1 * (1.f / HID);
    float var  = s2 * (1.f / HID) - mu * mu;
    float rstd = rsqrtf(var + LN_EPS);
    #pragma unroll
    for (int i = 0; i < 4; ++i) {
        int col = tid + i * 256;
        out[s * HID + col] = (x[i] - mu) * rstd * w[col] + b[col];
    }
}

extern "C" void kernel_launch(void* const* d_in, const int* in_sizes, int n_in,
                              void* d_out, int out_size, void* d_ws, size_t ws_size,
                              hipStream_t stream) {
    const float* X   = (const float*)d_in[0];
    const float* sd  = (const float*)d_in[1];
    const int*   msk = (const int*)d_in[2];
    const float* Wq  = (const float*)d_in[3];
    const float* Wk  = (const float*)d_in[4];
    const float* Wv  = (const float*)d_in[5];
    const float* Wo  = (const float*)d_in[6];
    const float* Wsp = (const float*)d_in[7];
    const float* bsp = (const float*)d_in[8];
    const float* lw  = (const float*)d_in[9];
    const float* lb  = (const float*)d_in[10];
    float* out = (float*)d_out;

    char* ws = (char*)d_ws;
    const size_t MB = 1ull << 20;
    float*          semb  = (float*)(ws);                     // 4 KB
    float*          Lbuf  = (float*)(ws + (1ull << 16));      // 128 KB @64K
    unsigned short* Xb    = (unsigned short*)(ws + 1 * MB);   // 8 MB bf16 X
    unsigned short* kvin  = (unsigned short*)(ws + 9 * MB);   // 8 MB
    unsigned short* Qb    = (unsigned short*)(ws + 17 * MB);  // 8 MB (dead after flash)
    unsigned short* Kb    = (unsigned short*)(ws + 25 * MB);  // 8 MB (dead after flash)
    unsigned short* Vt    = (unsigned short*)(ws + 33 * MB);  // 8 MB [HID][S_LEN]
    unsigned short* ctx   = (unsigned short*)(ws + 41 * MB);  // 8 MB
    unsigned short* Wqb   = (unsigned short*)(ws + 49 * MB);  // 2 MB
    unsigned short* Wkb   = (unsigned short*)(ws + 51 * MB);  // 2 MB
    unsigned short* Wvb   = (unsigned short*)(ws + 53 * MB);  // 2 MB
    unsigned short* Wob   = (unsigned short*)(ws + 55 * MB);  // 2 MB
    float*          resf  = (float*)(ws + 17 * MB);           // 16 MB, overlays dead Qb/Kb
    unsigned short* Opart = (unsigned short*)(ws + 57 * MB);  // 32 MB bf16 [4][S][H] -> 89 MB total

    const int SH = S_LEN * HID;   // 4M
    const int WW = HID * HID;     // 1M

    // weights->bf16 (z=0..3) + semb (z=4) in one dispatch
    k_cvt4s<<<dim3(WW / 8 / 256, 5), dim3(256), 0, stream>>>(
        Wq, Wk, Wv, Wo, Wqb, Wkb, Wvb, Wob, Wsp, sd, bsp, semb);

    k_kvin<<<dim3(SH / 8 / 256), dim3(256), 0, stream>>>(X, semb, Xb, kvin);

    // fused Q/K/V projections, 128x128 tiles: z=0 Q, z=1 K, z=2 V^T  -> 768 blocks, 3/CU
    k_gemm_qkv<<<dim3(256, 1, 3), dim3(256), 0, stream>>>(Xb, kvin, Wqb, Wkb, Wvb, Qb, Kb, Vt);

    // XCD swizzle: x = head*NSPLIT+split (8), y = qtile (64)
    k_flash<<<dim3(NHEAD * NSPLIT, S_LEN / 64), dim3(256), 0, stream>>>(
        Qb, Kb, Vt, msk, Opart, Lbuf);

    k_combine<<<dim3(SH / 256), dim3(256), 0, stream>>>(Opart, Lbuf, ctx);
    k_gemm_o<<<dim3(512), dim3(256), 0, stream>>>(ctx, Wob, resf, X);
    k_ln<<<dim3(S_LEN), dim3(256), 0, stream>>>(resf, lw, lb, out);
}